// Round 3
// baseline (2923.285 us; speedup 1.0000x reference)
//
#include <hip/hip_runtime.h>

// fp32 I/O. N=32, C=64, T=256, V=50, H=8, hc=8
// plane = T*V = 12800, n-stride = 819200, score K-dim = hc*T = 2048.
// n processed in 4 groups of 8; k tensor staged in d_out (same fp32 size),
// overwritten by K3(g) only after K2(g) consumed it (stream order).
// v-projection folded into o-projection: W2[s,o,a] = sum_c ow[o,s*64+c]*vw[c,a],
// ovb[s,o] = sum_c ow[o,s*64+c]*vb[c]  ->  K3 reads x_kv directly, no v tensor.

// ---------------------------------------------------------------------------
// K0: wT (q/k weight transpose, [c][o]) + W2 + ovb
__global__ void k0_prep(const float* __restrict__ qw, const float* __restrict__ kw,
                        const float* __restrict__ vw, const float* __restrict__ vb,
                        const float* __restrict__ ow,
                        float* __restrict__ wT, float* __restrict__ W2,
                        float* __restrict__ ovb)
{
    int i = threadIdx.x + blockIdx.x * 256;
    if (i < 4096){
        int o = i >> 6, c = i & 63;
        wT[c*64 + o]        = qw[i];
        wT[4096 + c*64 + o] = kw[i];
    } else if (i < 36864){
        int j = i - 4096;
        int s = j >> 12, o = (j >> 6) & 63, a = j & 63;
        float acc = 0.f;
        for (int c = 0; c < 64; ++c)
            acc += ow[o*512 + s*64 + c] * vw[c*64 + a];
        W2[j] = acc;
    } else if (i < 37376){
        int j = i - 36864;
        int s = j >> 6, o = j & 63;
        float acc = 0.f;
        for (int c = 0; c < 64; ++c)
            acc += ow[o*512 + s*64 + c] * vb[c];
        ovb[j] = acc;
    }
}

// ---------------------------------------------------------------------------
// K1: q,k projections for one n-group. Block = (pos-tile, n_rel).
// q -> qchunk (group-relative), k -> d_out (absolute).
__global__ __launch_bounds__(256, 2) void k1_qk(
    const float* __restrict__ xq, const float* __restrict__ xkv,
    const float* __restrict__ wT,
    const float* __restrict__ qb, const float* __restrict__ kb,
    float* __restrict__ qo, float* __restrict__ ko, int n0)
{
    __shared__ float sx[64*256];              // 64 KB, one tensor at a time
    const int nrel = blockIdx.y;
    const int nabs = n0 + nrel;
    const int p0   = blockIdx.x * 256;
    const int tid  = threadIdx.x;
    const size_t abase = (size_t)nabs * 819200;
    const size_t rbase = (size_t)nrel * 819200;

    for (int phase = 0; phase < 2; ++phase){
        const float* src  = phase ? xkv : xq;
        const float* bias = phase ? kb : qb;
        const float* w    = phase ? (wT + 4096) : wT;

        if (phase) __syncthreads();           // readers of prev sx done
        {   // stage 64x256 fp32 tile, float4 coalesced
            const float* g = src + abase + p0;
            #pragma unroll
            for (int j = 0; j < 16; ++j){
                int i4 = tid + j*256;         // 0..4095 float4s
                int c = i4 >> 6, m4 = i4 & 63;
                float4 val = *(const float4*)(g + (size_t)c*12800 + m4*4);
                *(float4*)(&sx[c*256 + m4*4]) = val;
            }
        }
        __syncthreads();

        for (int h = 0; h < 2; ++h){
            const int o0 = h*32;
            float acc[32];
            #pragma unroll
            for (int j = 0; j < 32; ++j) acc[j] = bias[o0+j];
            for (int c = 0; c < 64; ++c){
                float xv = sx[c*256 + tid];
                const float* row = w + c*64 + o0;
                #pragma unroll
                for (int j = 0; j < 32; ++j) acc[j] += row[j] * xv;
            }
            float* dst = phase ? (ko + abase) : (qo + rbase);
            #pragma unroll
            for (int j = 0; j < 32; ++j)
                dst[(size_t)(o0+j)*12800 + p0 + tid] = acc[j];
        }
    }
}

// ---------------------------------------------------------------------------
// K2p: partial scores. Block = n_rel*32 + s*4 + kq (256 blocks/group).
// Each wave sums 128 K-rows; q per-lane, k rows wave-uniform (scalar loads).
__global__ __launch_bounds__(256, 2) void k2_partial(
    const float* __restrict__ qc, const float* __restrict__ kd,
    float* __restrict__ pscore, int n0)
{
    __shared__ float red[4*2500];             // 40 KB
    const int bid  = blockIdx.x;
    const int kq   = bid & 3;
    const int s    = (bid >> 2) & 7;
    const int nrel = bid >> 5;
    const int tid  = threadIdx.x;
    const int wave = __builtin_amdgcn_readfirstlane(tid >> 6);
    const int lane = tid & 63;
    const float* qf = qc + (size_t)nrel * 819200 + (size_t)s * 102400;
    const float* kf = kd + (size_t)(n0 + nrel) * 819200 + (size_t)s * 102400;

    float acc[50];
    #pragma unroll
    for (int w = 0; w < 50; ++w) acc[w] = 0.f;

    if (lane < 50){
        const int r0 = kq*512 + wave*128;
        for (int kk = r0; kk < r0 + 128; kk += 4){
            float qv[4];
            #pragma unroll
            for (int t = 0; t < 4; ++t) qv[t] = qf[(size_t)(kk+t)*50 + lane];
            #pragma unroll
            for (int t = 0; t < 4; ++t){
                const float* kr = kf + (size_t)(kk+t)*50;   // wave-uniform
                #pragma unroll
                for (int w = 0; w < 50; ++w) acc[w] += qv[t] * kr[w];
            }
        }
        #pragma unroll
        for (int w = 0; w < 50; ++w) red[wave*2500 + lane*50 + w] = acc[w];
    }
    __syncthreads();

    for (int i = tid; i < 2500; i += 256)
        pscore[(size_t)bid*2500 + i] = red[i] + red[2500+i] + red[5000+i] + red[7500+i];
}

// ---------------------------------------------------------------------------
// K2f: attn = tanh(score/2048)*alpha + gattn. Block = n_rel*8 + s.
__global__ void k2_final(const float* __restrict__ pscore,
                         const float* __restrict__ alphas, const float* __restrict__ gattn,
                         float* __restrict__ attnc)
{
    const int b = blockIdx.x;
    const int s = b & 7;
    const float inv = 1.0f / 2048.0f;
    const float alpha = alphas[s];
    for (int i = threadIdx.x; i < 2500; i += 256){
        float sum = pscore[(size_t)(b*4+0)*2500 + i] + pscore[(size_t)(b*4+1)*2500 + i]
                  + pscore[(size_t)(b*4+2)*2500 + i] + pscore[(size_t)(b*4+3)*2500 + i];
        attnc[(size_t)b*2500 + i] = tanhf(sum * inv) * alpha + gattn[i];
    }
}

// ---------------------------------------------------------------------------
// K3: out[o,t,w] = ob[o] + sum_s [ ovb[s,o]*sum_u attn + sum_u attn[s,u,w] *
//                  (sum_a W2[s,o,a]*x_kv[a,t,u]) ]  (ovb folded into P init)
// Block = (t-tile, n_rel); lane = o; wave = t within tile (uniform).
// x_kv rows and attn rows wave-uniform -> scalar loads.
__global__ __launch_bounds__(256, 3) void k3_out(
    const float* __restrict__ xkv, const float* __restrict__ attnc,
    const float* __restrict__ W2, const float* __restrict__ ovb,
    const float* __restrict__ ob, float* __restrict__ out, int n0)
{
    __shared__ float sw2[64*65];              // 16.6 KB, stride 65
    const int nrel = blockIdx.y;
    const int nabs = n0 + nrel;
    const int tb   = blockIdx.x;
    const int tid  = threadIdx.x;
    const int o    = tid & 63;
    const int ttu  = __builtin_amdgcn_readfirstlane(tid >> 6);
    const int trow = tb*4 + ttu;
    const size_t abase = (size_t)nabs * 819200;

    float oacc[50];
    #pragma unroll
    for (int w = 0; w < 50; ++w) oacc[w] = 0.f;

    for (int s = 0; s < 8; ++s){
        __syncthreads();
        for (int j = tid; j < 4096; j += 256){
            int oo = j >> 6, aa = j & 63;
            sw2[oo*65 + aa] = W2[s*4096 + j];
        }
        __syncthreads();

        // ---- phase P: P[u] = ovb[s,o] + sum_a W2_s[o,a] * x_kv[a,trow,u] ----
        float P[50];
        const float pb = ovb[s*64 + o];
        #pragma unroll
        for (int u = 0; u < 50; ++u) P[u] = pb;

        const float* xbase = xkv + abase + (size_t)trow * 50;
        for (int a = 0; a < 64; ++a){
            const float* xr = xbase + (size_t)a * 12800;    // wave-uniform
            float w2v = sw2[o*65 + a];
            #pragma unroll
            for (int u = 0; u < 50; ++u) P[u] += w2v * xr[u];
        }

        // ---- phase C: oacc[w] += P[u] * attn[s,u,w] ----
        const float* ar = attnc + (size_t)(nrel*8 + s) * 2500; // wave-uniform
        #pragma unroll
        for (int u = 0; u < 50; ++u){
            float pv = P[u];
            #pragma unroll
            for (int w = 0; w < 50; ++w) oacc[w] += pv * ar[u*50 + w];
        }
    }

    const float bias = ob[o];
    float* op = out + abase + (size_t)o*12800 + (size_t)trow*50;
    #pragma unroll
    for (int w = 0; w < 50; ++w) op[w] = oacc[w] + bias;
}

// ---------------------------------------------------------------------------
extern "C" void kernel_launch(void* const* d_in, const int* in_sizes, int n_in,
                              void* d_out, int out_size, void* d_ws, size_t ws_size,
                              hipStream_t stream)
{
    const float* x_q    = (const float*)d_in[0];
    const float* x_kv   = (const float*)d_in[1];
    const float* q_w    = (const float*)d_in[2];
    const float* q_b    = (const float*)d_in[3];
    const float* k_w    = (const float*)d_in[4];
    const float* k_b    = (const float*)d_in[5];
    const float* v_w    = (const float*)d_in[6];
    const float* v_b    = (const float*)d_in[7];
    const float* o_w    = (const float*)d_in[8];
    const float* o_b    = (const float*)d_in[9];
    const float* alphas = (const float*)d_in[10];
    const float* gattn  = (const float*)d_in[11];
    float* out = (float*)d_out;

    // ws layout (29.6 MB):
    char* ws = (char*)d_ws;
    float* qchunk = (float*)(ws);                  // 26,214,400 B (8n q fp32)
    float* pscore = (float*)(ws + 26214400);       //  2,560,000 B
    float* attnc  = (float*)(ws + 28774400);       //    640,000 B
    float* wT     = (float*)(ws + 29414400);       //     32,768 B
    float* W2     = (float*)(ws + 29447168);       //    131,072 B
    float* ovb    = (float*)(ws + 29578240);       //      2,048 B

    k0_prep<<<146, 256, 0, stream>>>(q_w, k_w, v_w, v_b, o_w, wT, W2, ovb);

    for (int g = 0; g < 4; ++g){
        const int n0 = g * 8;
        k1_qk<<<dim3(50, 8), 256, 0, stream>>>(x_q, x_kv, wT, q_b, k_b,
                                               qchunk, out /*k in d_out*/, n0);
        k2_partial<<<256, 256, 0, stream>>>(qchunk, (const float*)d_out, pscore, n0);
        k2_final<<<64, 256, 0, stream>>>(pscore, alphas, gattn, attnc);
        k3_out<<<dim3(64, 8), 256, 0, stream>>>(x_kv, attnc, W2, ovb, o_b, out, n0);
    }
}